// Round 12
// baseline (445.435 us; speedup 1.0000x reference)
//
#include <hip/hip_runtime.h>
#include <hip/hip_bf16.h>
#include <hip/hip_cooperative_groups.h>

#define S 64
#define B 32
#define HID 16
#define EMB 32
#define V 50257
#define VP4 51200               // padded cols: 8 cg x 25 chunks x 256
#define M 2048                  // S*B rows
#define NCG 8
#define TPW 100                 // tiles per wave per col-group (phase 1)
#define CPG 25                  // 256-col chunks per col-group (phase 2)
#define WB_STRIDE (496*256)     // Wb-convert grid stride (blocks 16..511)

namespace cgrp = cooperative_groups;

using bf16x8 = __attribute__((ext_vector_type(8))) __bf16;
using f32x4  = __attribute__((ext_vector_type(4))) float;

// ---- R9 pass2 helpers, verbatim -------------------------------------------------
__device__ __forceinline__ void p2_load(const __bf16* __restrict__ Wb,
                                        const float* __restrict__ bias,
                                        int chunk, int wave, int lr, int kg,
                                        bf16x8* wf, float* bc) {
    const int t0 = chunk * 16 + wave * 4;
    #pragma unroll
    for (int q = 0; q < 4; ++q) {
        wf[q] = *reinterpret_cast<const bf16x8*>(Wb + ((t0 + q) * 16 + lr) * 32 + kg * 8);
        bc[q] = bias[(t0 + q) * 16 + lr];
    }
}

template <bool GUARD>
__device__ __forceinline__ void p2_cs(const bf16x8* wf, const float* bc, bf16x8 a,
                                      const float* lzr, int chunk, int wave,
                                      int lane, int lr, int kg, int m0,
                                      float* __restrict__ out, float (*st)[68]) {
    const f32x4 zero = {0.f, 0.f, 0.f, 0.f};
    #pragma unroll
    for (int q = 0; q < 4; ++q) {
        f32x4 d = __builtin_amdgcn_mfma_f32_16x16x32_bf16(a, wf[q], zero, 0, 0, 0);
        const int cl = q * 16 + lr;
        #pragma unroll
        for (int r = 0; r < 4; ++r)
            st[kg * 4 + r][cl] = d[r] + bc[q] - lzr[r];
    }
    asm volatile("s_waitcnt lgkmcnt(0)" ::: "memory");   // wave-internal fence
    __builtin_amdgcn_sched_barrier(0);                   // rule 18
    const int cb0 = chunk * 256 + wave * 64;
    const int vcol = cb0 + lane;
    float* p = out + (size_t)m0 * V + vcol;
    #pragma unroll
    for (int r = 0; r < 16; ++r) {
        if (!GUARD || vcol < V)
            p[(size_t)r * V] = st[r][lane];
    }
}

// ---- the single fused cooperative kernel ----------------------------------------
__global__ __launch_bounds__(256, 2) void k_all(
        const int* __restrict__ idx, const float* __restrict__ emb,
        const float* __restrict__ W_lr, const float* __restrict__ b_lr,
        const float* __restrict__ W_rl, const float* __restrict__ b_rl,
        const float* __restrict__ W_ho, const float* __restrict__ b_ho,
        const float* __restrict__ h0,
        __bf16* __restrict__ Wb, float* __restrict__ bias,
        __bf16* __restrict__ hb, float* __restrict__ P,
        float* __restrict__ Zp, float* __restrict__ out) {
    __shared__ float Psh[S * 4 * HID];       // 16 KB (rnn)
    __shared__ float hsh[4][17];
    __shared__ float red[2][4][16];
    __shared__ float lzsh[2][16];
    __shared__ float stg[2][4][16][68];      // 34.8 KB (phase-2 slabs)

    const int cg = blockIdx.x, ry = blockIdx.y;   // grid (8, 64)
    const int bid = cg + NCG * ry;                // 0..511
    const int t = threadIdx.x;
    const int gtid = bid * 256 + t;               // 0..131071

    // ---------------- A0: bias pad + P projection --------------------------------
    if (gtid < VP4) bias[gtid] = (gtid < V) ? b_ho[gtid] : -1e30f;
    if (gtid < 2 * M * HID) {                     // 65536
        const int i = gtid;
        const int dir = i >> 15, r = i & 32767, m = r >> 4, j = r & 15;
        const float* W  = dir ? W_rl : W_lr;
        const float* bb = dir ? b_rl : b_lr;
        const int tok = idx[m];
        const float4* er = reinterpret_cast<const float4*>(emb + (size_t)tok * EMB);
        const float4* wr = reinterpret_cast<const float4*>(W + j * (EMB + HID));
        float acc = bb[j];
        #pragma unroll
        for (int q = 0; q < 8; ++q) {
            float4 e4 = er[q], w4 = wr[q];
            acc += e4.x * w4.x + e4.y * w4.y + e4.z * w4.z + e4.w * w4.w;
        }
        P[i] = acc;
    }
    __threadfence();
    cgrp::this_grid().sync();

    // ---------------- A1: rnn (blocks 0-15, wave 0)  ∥  Wb convert (rest) --------
    if (bid < 16) {
        if (t < 64) {
            const int dir = bid >> 3, bq = bid & 7;
            const int bl = t >> 4, j = t & 15;
            const int b = bq * 4 + bl;
            {
                const float4* Pg4 = reinterpret_cast<const float4*>(P);
                float4* Ps4 = reinterpret_cast<float4*>(Psh);
                #pragma unroll
                for (int i = 0; i < 16; ++i) {
                    int s = (t >> 4) + 4 * i;
                    Ps4[t + 64 * i] = Pg4[dir * 8192 + s * 128 + bq * 16 + (t & 15)];
                }
            }
            const float* Wd = (dir ? W_rl : W_lr) + j * (EMB + HID) + EMB;
            float wh[16];
            #pragma unroll
            for (int q = 0; q < 4; ++q) {
                float4 w4 = *reinterpret_cast<const float4*>(Wd + q * 4);
                wh[q * 4 + 0] = w4.x; wh[q * 4 + 1] = w4.y;
                wh[q * 4 + 2] = w4.z; wh[q * 4 + 3] = w4.w;
            }
            float hcur = h0[j];
            hsh[bl][j] = hcur;
            for (int step = 0; step < S; ++step) {
                const int s = dir ? (S - 1 - step) : step;
                hb[(s * B + b) * 32 + dir * HID + j] = (__bf16)hcur;   // pre-state
                float acc = Psh[s * 64 + bl * 16 + j];
                #pragma unroll
                for (int k = 0; k < HID; ++k) acc += wh[k] * hsh[bl][k];
                hcur = tanhf(acc);
                hsh[bl][j] = hcur;
            }
        }
    } else {
        for (int i = (bid - 16) * 256 + t; i < VP4 * EMB; i += WB_STRIDE) {
            int v = i >> 5;
            Wb[i] = (v < V) ? (__bf16)W_ho[i] : (__bf16)0.f;
        }
    }
    __threadfence();
    cgrp::this_grid().sync();

    // ---------------- phase 1: sum(exp(logit)) per (cg, row) ---------------------
    const int wave = t >> 6, lane = t & 63;
    const int lr = lane & 15, kg = lane >> 4;
    const int rt0 = ry * 2;
    const int tb = cg * 400 + wave * TPW;
    const f32x4 zero = {0.f, 0.f, 0.f, 0.f};
    #pragma unroll
    for (int h = 0; h < 2; ++h) {
        const int m0 = (rt0 + h) * 16;
        const bf16x8 a = *reinterpret_cast<const bf16x8*>(hb + (m0 + lr) * 32 + kg * 8);
        float s = 0.f;
        for (int tt = tb; tt < tb + TPW; ++tt) {
            bf16x8 wf = *reinterpret_cast<const bf16x8*>(Wb + (tt * 16 + lr) * 32 + kg * 8);
            f32x4 b4 = *reinterpret_cast<const f32x4*>(bias + tt * 16 + kg * 4);
            f32x4 d = __builtin_amdgcn_mfma_f32_16x16x32_bf16(wf, a, zero, 0, 0, 0);
            s += __expf(d[0] + b4[0]) + __expf(d[1] + b4[1]) +
                 __expf(d[2] + b4[2]) + __expf(d[3] + b4[3]);
        }
        s += __shfl_xor(s, 16);          // combine the 4 kg groups (same m-row)
        s += __shfl_xor(s, 32);
        if (lane < 16) red[h][wave][lane] = s;
    }
    __syncthreads();
    if (t < 32) {
        const int h = t >> 4, row = t & 15;
        float z = red[h][0][row] + red[h][1][row] + red[h][2][row] + red[h][3][row];
        __hip_atomic_store(&Zp[cg * M + (rt0 + h) * 16 + row], z,
                           __ATOMIC_RELAXED, __HIP_MEMORY_SCOPE_AGENT);
    }
    __threadfence();
    cgrp::this_grid().sync();

    // ---------------- logZ for this block's 32 rows ------------------------------
    if (t < 32) {
        const int h = t >> 4, row = t & 15;
        float z = 0.f;
        #pragma unroll
        for (int c = 0; c < NCG; ++c)
            z += __hip_atomic_load(&Zp[c * M + (rt0 + h) * 16 + row],
                                   __ATOMIC_RELAXED, __HIP_MEMORY_SCOPE_AGENT);
        lzsh[h][row] = __logf(z);
    }
    __syncthreads();

    // ---------------- phase 2: R9 pass2, verbatim --------------------------------
    float (*stA)[68] = stg[0][wave];
    float (*stB)[68] = stg[1][wave];
    const int c0 = cg * CPG;
    #pragma unroll
    for (int h = 0; h < 2; ++h) {
        const int m0 = (rt0 + h) * 16;
        const bf16x8 a = *reinterpret_cast<const bf16x8*>(hb + (m0 + lr) * 32 + kg * 8);
        float lzr[4];
        #pragma unroll
        for (int r = 0; r < 4; ++r) lzr[r] = lzsh[h][kg * 4 + r];

        bf16x8 wfA[4], wfB[4];
        float bcA[4], bcB[4];
        p2_load(Wb, bias, c0, wave, lr, kg, wfA, bcA);
        if (cg < 7) {
            for (int g = 0; g < 12; ++g) {
                p2_load(Wb, bias, c0 + 2 * g + 1, wave, lr, kg, wfB, bcB);
                p2_cs<false>(wfA, bcA, a, lzr, c0 + 2 * g, wave, lane, lr, kg, m0, out, stA);
                p2_load(Wb, bias, c0 + 2 * g + 2, wave, lr, kg, wfA, bcA);
                p2_cs<false>(wfB, bcB, a, lzr, c0 + 2 * g + 1, wave, lane, lr, kg, m0, out, stB);
            }
            p2_cs<false>(wfA, bcA, a, lzr, c0 + 24, wave, lane, lr, kg, m0, out, stA);
        } else {
            for (int g = 0; g < 12; ++g) {
                p2_load(Wb, bias, c0 + 2 * g + 1, wave, lr, kg, wfB, bcB);
                p2_cs<true>(wfA, bcA, a, lzr, c0 + 2 * g, wave, lane, lr, kg, m0, out, stA);
                p2_load(Wb, bias, c0 + 2 * g + 2, wave, lr, kg, wfA, bcA);
                p2_cs<true>(wfB, bcB, a, lzr, c0 + 2 * g + 1, wave, lane, lr, kg, m0, out, stB);
            }
            p2_cs<true>(wfA, bcA, a, lzr, c0 + 24, wave, lane, lr, kg, m0, out, stA);
        }
    }
}

extern "C" void kernel_launch(void* const* d_in, const int* in_sizes, int n_in,
                              void* d_out, int out_size, void* d_ws, size_t ws_size,
                              hipStream_t stream) {
    const int*   idx       = (const int*)d_in[0];
    const float* embedding = (const float*)d_in[1];
    const float* W_lr      = (const float*)d_in[2];
    const float* b_lr      = (const float*)d_in[3];
    const float* W_rl      = (const float*)d_in[4];
    const float* b_rl      = (const float*)d_in[5];
    const float* W_ho      = (const float*)d_in[6];
    const float* b_ho      = (const float*)d_in[7];
    const float* h0        = (const float*)d_in[8];
    float* out = (float*)d_out;

    char* ws = (char*)d_ws;
    size_t off = 0;
    __bf16* Wb   = (__bf16*)(ws + off); off += (size_t)VP4 * EMB * 2;   // 3,276,800
    float*  bias = (float*)(ws + off);  off += (size_t)VP4 * 4;         //   204,800
    __bf16* hb   = (__bf16*)(ws + off); off += (size_t)M * 32 * 2;      //   131,072
    float*  P    = (float*)(ws + off);  off += (size_t)2 * M * HID * 4; //   262,144
    float*  Zp   = (float*)(ws + off);  off += (size_t)NCG * M * 4;     //    65,536

    void* kargs[] = { (void*)&idx, (void*)&embedding,
                      (void*)&W_lr, (void*)&b_lr, (void*)&W_rl, (void*)&b_rl,
                      (void*)&W_ho, (void*)&b_ho, (void*)&h0,
                      (void*)&Wb, (void*)&bias, (void*)&hb, (void*)&P,
                      (void*)&Zp, (void*)&out };
    hipLaunchCooperativeKernel((const void*)k_all, dim3(NCG, 64), dim3(256),
                               kargs, 0, stream);
}

// Round 13
// 181.568 us; speedup vs baseline: 2.4533x; 2.4533x over previous
//
#include <hip/hip_runtime.h>
#include <hip/hip_bf16.h>

#define S 64
#define B 32
#define HID 16
#define EMB 32
#define V 50257
#define NCB 197                 // pass1 column blocks of 256 cols (50432 scanned)
#define NCG2 16                 // pass2 column groups
#define CPG2 13                 // 256-col chunks per group
#define VP5 (NCG2*CPG2*256)     // 53248 padded cols
#define M 2048                  // S*B rows
#define PREP_BLOCKS (VP5*EMB/256)   // 6656 exactly
#define NRG 8                   // row groups for pass1
#define RT_PER (128/NRG)

using bf16x8 = __attribute__((ext_vector_type(8))) __bf16;
using f32x4  = __attribute__((ext_vector_type(4))) float;

// ---------------- K1: fused prep ---------------------------------------------------
__global__ void k_prep(const float* __restrict__ W_ho, const float* __restrict__ b_ho,
                       const int* __restrict__ idx, const float* __restrict__ emb,
                       const float* __restrict__ W_lr, const float* __restrict__ b_lr,
                       const float* __restrict__ W_rl, const float* __restrict__ b_rl,
                       __bf16* __restrict__ Wb, float* __restrict__ bias,
                       float* __restrict__ P) {
    const int bx = blockIdx.x;
    if (bx < PREP_BLOCKS) {
        int i = bx * 256 + threadIdx.x;          // < VP5*EMB exactly
        if (i < VP5) bias[i] = (i < V) ? b_ho[i] : -1e30f;
        int v = i >> 5;
        Wb[i] = (v < V) ? (__bf16)W_ho[i] : (__bf16)0.f;
    } else {
        int i = (bx - PREP_BLOCKS) * 256 + threadIdx.x;   // 0..65535
        const int dir = i >> 15, r = i & 32767, m = r >> 4, j = r & 15;
        const float* W  = dir ? W_rl : W_lr;
        const float* bb = dir ? b_rl : b_lr;
        const int tok = idx[m];
        const float4* er = reinterpret_cast<const float4*>(emb + (size_t)tok * EMB);
        const float4* wr = reinterpret_cast<const float4*>(W + j * (EMB + HID));
        float acc = bb[j];
        #pragma unroll
        for (int q = 0; q < 8; ++q) {
            float4 e4 = er[q], w4 = wr[q];
            acc += e4.x * w4.x + e4.y * w4.y + e4.z * w4.z + e4.w * w4.w;
        }
        P[i] = acc;
    }
}

// ---------------- K2: serial RNN scans — recurrence via __shfl (no LDS h) ----------
__global__ void k_rnn(const float* __restrict__ P,
                      const float* __restrict__ W_lr, const float* __restrict__ W_rl,
                      const float* __restrict__ h0, __bf16* __restrict__ hcat) {
    __shared__ float Psh[S * 4 * HID];   // 16 KB: [s][bl][j]
    const int t = threadIdx.x;           // 0..63, single wave
    const int dir = blockIdx.x >> 3, bq = blockIdx.x & 7;
    const int bl = t >> 4, j = t & 15;
    const int b = bq * 4 + bl;
    {
        const float4* Pg4 = reinterpret_cast<const float4*>(P);
        float4* Ps4 = reinterpret_cast<float4*>(Psh);
        #pragma unroll
        for (int i = 0; i < 16; ++i) {
            int s = (t >> 4) + 4 * i;
            Ps4[t + 64 * i] = Pg4[dir * 8192 + s * 128 + bq * 16 + (t & 15)];
        }
    }
    const float* Wd = (dir ? W_rl : W_lr) + j * (EMB + HID) + EMB;
    float wh[16];
    #pragma unroll
    for (int q = 0; q < 4; ++q) {
        float4 w4 = *reinterpret_cast<const float4*>(Wd + q * 4);
        wh[q * 4 + 0] = w4.x; wh[q * 4 + 1] = w4.y;
        wh[q * 4 + 2] = w4.z; wh[q * 4 + 3] = w4.w;
    }
    float hcur = h0[j];
    // h_k for this batch lives in lanes (t&48)+k — register-only recurrence.
    for (int step = 0; step < S; ++step) {
        const int s = dir ? (S - 1 - step) : step;
        hcat[(s * B + b) * 32 + dir * HID + j] = (__bf16)hcur;   // pre-state
        float acc = Psh[s * 64 + bl * 16 + j];
        #pragma unroll
        for (int k = 0; k < HID; ++k)
            acc += wh[k] * __shfl(hcur, (t & 48) + k, 64);
        hcur = tanhf(acc);
    }
}

// ---------------- K3: pass 1 — Wb slice in registers, loop over row-tiles ----------
__global__ void k_pass1(const __bf16* __restrict__ hb, const __bf16* __restrict__ Wb,
                        const float* __restrict__ bias, float* __restrict__ partials) {
    const int cbx = blockIdx.x, rg = blockIdx.y;
    const int wave = threadIdx.x >> 6, lane = threadIdx.x & 63;
    const int lr = lane & 15, kg = lane >> 4;
    const int ttbase = cbx * 16 + wave * 4;
    bf16x8 wfrag[4]; float bc[4];
    #pragma unroll
    for (int q = 0; q < 4; ++q) {
        wfrag[q] = *reinterpret_cast<const bf16x8*>(Wb + ((ttbase + q) * 16 + lr) * 32 + kg * 8);
        bc[q] = bias[(ttbase + q) * 16 + lr];
    }
    __shared__ float red[4][16];
    const f32x4 zero = {0.f, 0.f, 0.f, 0.f};
    for (int rt = rg * RT_PER; rt < rg * RT_PER + RT_PER; ++rt) {
        const int m0 = rt * 16;
        const bf16x8 a = *reinterpret_cast<const bf16x8*>(hb + (m0 + lr) * 32 + kg * 8);
        float s0 = 0.f, s1 = 0.f, s2 = 0.f, s3 = 0.f;
        #pragma unroll
        for (int q = 0; q < 4; ++q) {
            f32x4 d = __builtin_amdgcn_mfma_f32_16x16x32_bf16(a, wfrag[q], zero, 0, 0, 0);
            s0 += __expf(d[0] + bc[q]);
            s1 += __expf(d[1] + bc[q]);
            s2 += __expf(d[2] + bc[q]);
            s3 += __expf(d[3] + bc[q]);
        }
        #pragma unroll
        for (int off = 1; off < 16; off <<= 1) {
            s0 += __shfl_xor(s0, off);
            s1 += __shfl_xor(s1, off);
            s2 += __shfl_xor(s2, off);
            s3 += __shfl_xor(s3, off);
        }
        if (lr == 0) {
            red[wave][kg * 4 + 0] = s0;
            red[wave][kg * 4 + 1] = s1;
            red[wave][kg * 4 + 2] = s2;
            red[wave][kg * 4 + 3] = s3;
        }
        __syncthreads();
        if (threadIdx.x < 16)
            partials[cbx * M + m0 + threadIdx.x] =
                red[0][threadIdx.x] + red[1][threadIdx.x] +
                red[2][threadIdx.x] + red[3][threadIdx.x];
        __syncthreads();
    }
}

// ---------------- K4: pass 2 — HIGH-OCCUPANCY single-buffer streaming --------------
// grid (16,128) = 2048 blocks; LDS 18.5 KB + launch_bounds(256,6) -> 6-8 blocks/CU
// = 24-32 waves/CU of store MLP (the one axis all prior rounds left untested).
// Same-wave LDS ops are pipe-ordered -> single slab is safe without extra waits.
__device__ __forceinline__ void p2_load(const __bf16* __restrict__ Wb,
                                        const float* __restrict__ bias,
                                        int chunk, int wave, int lr, int kg,
                                        bf16x8* wf, float* bc) {
    const int t0 = chunk * 16 + wave * 4;
    #pragma unroll
    for (int q = 0; q < 4; ++q) {
        wf[q] = *reinterpret_cast<const bf16x8*>(Wb + ((t0 + q) * 16 + lr) * 32 + kg * 8);
        bc[q] = bias[(t0 + q) * 16 + lr];
    }
}

template <bool GUARD>
__device__ __forceinline__ void p2_cs(const bf16x8* wf, const float* bc, bf16x8 a,
                                      const float* lzr, int chunk, int wave,
                                      int lane, int lr, int kg, int m0,
                                      float* __restrict__ out, float (*st)[68]) {
    const f32x4 zero = {0.f, 0.f, 0.f, 0.f};
    #pragma unroll
    for (int q = 0; q < 4; ++q) {
        f32x4 d = __builtin_amdgcn_mfma_f32_16x16x32_bf16(a, wf[q], zero, 0, 0, 0);
        const int cl = q * 16 + lr;
        #pragma unroll
        for (int r = 0; r < 4; ++r)
            st[kg * 4 + r][cl] = d[r] + bc[q] - lzr[r];
    }
    asm volatile("s_waitcnt lgkmcnt(0)" ::: "memory");   // wave-internal fence
    __builtin_amdgcn_sched_barrier(0);                   // rule 18
    const int cb0 = chunk * 256 + wave * 64;
    const int vcol = cb0 + lane;
    float* p = out + (size_t)m0 * V + vcol;
    #pragma unroll
    for (int r = 0; r < 16; ++r) {
        if (!GUARD || vcol < V)
            p[(size_t)r * V] = st[r][lane];
    }
}

__global__ __launch_bounds__(256, 6) void k_pass2(
        const __bf16* __restrict__ hb, const __bf16* __restrict__ Wb,
        const float* __restrict__ bias, const float* __restrict__ partials,
        float* __restrict__ out) {
    __shared__ float red[16][17];
    __shared__ float lzsh[16];
    __shared__ float stg[4][16][68];      // single-buffered wave-private slabs
    const int cg = blockIdx.x, rt = blockIdx.y;
    const int t = threadIdx.x;
    const int m0 = rt * 16;
    // ---- folded logZ reduction for this row-tile ----
    {
        const int row = t & 15, cch = t >> 4;
        float p = 0.f;
        for (int c = cch; c < NCB; c += 16) p += partials[c * M + m0 + row];
        red[cch][row] = p;
        __syncthreads();
        if (t < 16) {
            float tot = 0.f;
            #pragma unroll
            for (int k = 0; k < 16; ++k) tot += red[k][t];
            lzsh[t] = __logf(tot);
        }
        __syncthreads();
    }
    const int wave = t >> 6, lane = t & 63;
    const int lr = lane & 15, kg = lane >> 4;
    const bf16x8 a = *reinterpret_cast<const bf16x8*>(hb + (m0 + lr) * 32 + kg * 8);
    float lzr[4];
    #pragma unroll
    for (int r = 0; r < 4; ++r) lzr[r] = lzsh[kg * 4 + r];
    float (*st)[68] = stg[wave];
    const int c0 = cg * CPG2;             // chunks c0 .. c0+12

    bf16x8 wfA[4], wfB[4];
    float bcA[4], bcB[4];
    p2_load(Wb, bias, c0, wave, lr, kg, wfA, bcA);
    if (cg < 15) {
        for (int g = 0; g < 6; ++g) {
            p2_load(Wb, bias, c0 + 2 * g + 1, wave, lr, kg, wfB, bcB);
            p2_cs<false>(wfA, bcA, a, lzr, c0 + 2 * g, wave, lane, lr, kg, m0, out, st);
            p2_load(Wb, bias, c0 + 2 * g + 2, wave, lr, kg, wfA, bcA);
            p2_cs<false>(wfB, bcB, a, lzr, c0 + 2 * g + 1, wave, lane, lr, kg, m0, out, st);
        }
        p2_cs<false>(wfA, bcA, a, lzr, c0 + 12, wave, lane, lr, kg, m0, out, st);
    } else {
        for (int g = 0; g < 6; ++g) {
            p2_load(Wb, bias, c0 + 2 * g + 1, wave, lr, kg, wfB, bcB);
            p2_cs<true>(wfA, bcA, a, lzr, c0 + 2 * g, wave, lane, lr, kg, m0, out, st);
            p2_load(Wb, bias, c0 + 2 * g + 2, wave, lr, kg, wfA, bcA);
            p2_cs<true>(wfB, bcB, a, lzr, c0 + 2 * g + 1, wave, lane, lr, kg, m0, out, st);
        }
        p2_cs<true>(wfA, bcA, a, lzr, c0 + 12, wave, lane, lr, kg, m0, out, st);
    }
}

extern "C" void kernel_launch(void* const* d_in, const int* in_sizes, int n_in,
                              void* d_out, int out_size, void* d_ws, size_t ws_size,
                              hipStream_t stream) {
    const int*   idx       = (const int*)d_in[0];
    const float* embedding = (const float*)d_in[1];
    const float* W_lr      = (const float*)d_in[2];
    const float* b_lr      = (const float*)d_in[3];
    const float* W_rl      = (const float*)d_in[4];
    const float* b_rl      = (const float*)d_in[5];
    const float* W_ho      = (const float*)d_in[6];
    const float* b_ho      = (const float*)d_in[7];
    const float* h0        = (const float*)d_in[8];
    float* out = (float*)d_out;

    char* ws = (char*)d_ws;
    size_t off = 0;
    __bf16* Wb      = (__bf16*)(ws + off); off += (size_t)VP5 * EMB * 2;   // 3,407,872
    float*  bias    = (float*)(ws + off);  off += (size_t)VP5 * 4;         //   212,992
    __bf16* hb      = (__bf16*)(ws + off); off += (size_t)M * 32 * 2;      //   131,072
    float*  P       = (float*)(ws + off);  off += (size_t)2 * M * HID * 4; //   262,144
    float*  partials= (float*)(ws + off);  off += (size_t)NCB * M * 4;     // 1,613,824

    k_prep<<<PREP_BLOCKS + 256, 256, 0, stream>>>(W_ho, b_ho, idx, embedding,
                                                  W_lr, b_lr, W_rl, b_rl, Wb, bias, P);
    k_rnn<<<16, 64, 0, stream>>>(P, W_lr, W_rl, h0, hb);
    k_pass1<<<dim3(NCB, NRG), 256, 0, stream>>>(hb, Wb, bias, partials);
    k_pass2<<<dim3(NCG2, 128), 256, 0, stream>>>(hb, Wb, bias, partials, out);
}